// Round 1
// baseline (948.040 us; speedup 1.0000x reference)
//
#include <hip/hip_runtime.h>

#define NVP 10242
#define NV  40962
#define NF  81920
#define CH  64      // CIN = COUT = 64

// ---------------------------------------------------------------------------
// K0: relayout coeffs [o][c][k] -> coeffsT2 [(c*64+o)*4 + k]  (float4 per (c,o))
// so phase-2 of k_vertex reads one coalesced b128 per lane per c-iteration.
// ---------------------------------------------------------------------------
__global__ void k_coeffsT(const float* __restrict__ coeffs,
                          float* __restrict__ coeffsT2) {
    int t = blockIdx.x * 256 + threadIdx.x;   // 0..4095  (c*64+o)
    int c = t >> 6, o = t & 63;
    float4 v = *(const float4*)(coeffs + o * 256 + c * 4);
    *(float4*)(coeffsT2 + (size_t)t * 4) = v;
}

// ---------------------------------------------------------------------------
// K1: per-b transpose + pad:  x[c][v] (v<NVP) -> xin_t[v][c], ones for v>=NVP
// ---------------------------------------------------------------------------
__global__ void k_transpose(const float* __restrict__ x,
                            float* __restrict__ xin_t) {
    __shared__ float tile[64][65];           // +1 pad: conflict-free both ways
    int v0 = blockIdx.x * 64;
    int tx = threadIdx.x & 63;
    int ty = threadIdx.x >> 6;               // 0..3
    int v  = v0 + tx;
#pragma unroll
    for (int r = 0; r < 16; ++r) {
        int c = ty + r * 4;
        tile[tx][c] = (v < NVP) ? x[c * NVP + v] : 1.0f;   // coalesced over tx
    }
    __syncthreads();
#pragma unroll
    for (int r = 0; r < 16; ++r) {
        int vl = ty + r * 4;
        int vv = v0 + vl;
        if (vv < NV) xin_t[vv * 64 + tx] = tile[vl][tx];   // coalesced over tx
    }
}

// ---------------------------------------------------------------------------
// K2: per-b face gradients. One wave per face, lane = channel.
//   grad_d = sum_j G_vals[(d*NF+f)*3+j] * xin_t[G_cols[...]][c]
//   gf_ew[f][c] = sum_d grad_d * EW[f][d];  gf_ns likewise.
// ---------------------------------------------------------------------------
__global__ void __launch_bounds__(256) k_facegrad(
    const float* __restrict__ xin_t,
    const int*   __restrict__ G_cols, const float* __restrict__ G_vals,
    const float* __restrict__ EW,     const float* __restrict__ NS,
    float* __restrict__ gf_ew, float* __restrict__ gf_ns) {
    int f = (blockIdx.x * 256 + threadIdx.x) >> 6;   // global wave id = face
    int c = threadIdx.x & 63;
    float g[3];
#pragma unroll
    for (int d = 0; d < 3; ++d) {
        int base = (d * NF + f) * 3;
        float acc = 0.f;
#pragma unroll
        for (int j = 0; j < 3; ++j) {
            int   col = G_cols[base + j];     // wave-uniform -> broadcast
            float val = G_vals[base + j];
            acc += val * xin_t[col * 64 + c]; // coalesced 256B gather
        }
        g[d] = acc;
    }
    float ew = g[0] * EW[f * 3 + 0] + g[1] * EW[f * 3 + 1] + g[2] * EW[f * 3 + 2];
    float ns = g[0] * NS[f * 3 + 0] + g[1] * NS[f * 3 + 1] + g[2] * NS[f * 3 + 2];
    gf_ew[f * 64 + c] = ew;
    gf_ns[f * 64 + c] = ns;
}

// ---------------------------------------------------------------------------
// K3: per-b vertex kernel. Block = 256 thr (4 waves), tile = 32 vertices.
// Phase 1 (lane = channel): build feat (xin, lap, gv_ew, gv_ns) -> LDS.
//   LDS layout: smem[c*132 + vloc*4 + k]  (132 = 128+4 pad -> <=8-way conflicts)
// Phase 2 (lane = o): out[v][o] = bias[o] + sum_{c,k} feat[v][c][k]*coeffs[o][c][k]
//   8 vertices per wave, feat read as uniform-broadcast b128.
// Epilogue: LDS transpose -> coalesced store to out[o][v].
// ---------------------------------------------------------------------------
#define ROWS 132
__global__ void __launch_bounds__(256) k_vertex(
    const float* __restrict__ xin_t,
    const int*   __restrict__ L_cols,   const float* __restrict__ L_vals,
    const int*   __restrict__ F2V_cols, const float* __restrict__ F2V_vals,
    const float* __restrict__ gf_ew,    const float* __restrict__ gf_ns,
    const float* __restrict__ coeffsT2, const float* __restrict__ bias,
    float* __restrict__ out) {
    __shared__ float smem[64 * ROWS];          // 33,792 B; reused for outT
    int w    = threadIdx.x >> 6;               // wave 0..3
    int lane = threadIdx.x & 63;
    int vb   = blockIdx.x * 32;

    // ---- phase 1: feat build (lane = channel c) ----
    int c = lane;
#pragma unroll
    for (int i = 0; i < 8; ++i) {
        int vloc = i * 4 + w;
        int v    = vb + vloc;
        int vc   = (v < NV) ? v : (NV - 1);
        float f0 = xin_t[vc * 64 + c];
        float lap = 0.f;
        int lb = vc * 7;
#pragma unroll
        for (int j = 0; j < 7; ++j) {
            int   col = L_cols[lb + j];
            float val = L_vals[lb + j];
            lap += val * xin_t[col * 64 + c];
        }
        float ew = 0.f, ns = 0.f;
        int fb = vc * 6;
#pragma unroll
        for (int j = 0; j < 6; ++j) {
            int   col = F2V_cols[fb + j];
            float val = F2V_vals[fb + j];
            ew += val * gf_ew[col * 64 + c];
            ns += val * gf_ns[col * 64 + c];
        }
        *(float4*)&smem[c * ROWS + vloc * 4] = make_float4(f0, lap, ew, ns);
    }
    __syncthreads();

    // ---- phase 2: channel-mix GEMM (lane = o), 8 vertices per wave ----
    int o = lane;
    float acc[8];
    float bo = bias[o];
#pragma unroll
    for (int j = 0; j < 8; ++j) acc[j] = bo;
    int vbase = w * 8;
#pragma unroll 4
    for (int cc = 0; cc < 64; ++cc) {
        float4 wv = *(const float4*)(coeffsT2 + (size_t)(cc * 64 + o) * 4);
        const float* basep = &smem[cc * ROWS + vbase * 4];
#pragma unroll
        for (int j = 0; j < 8; ++j) {
            float4 ft = *(const float4*)(basep + j * 4);   // uniform broadcast
            acc[j] += ft.x * wv.x + ft.y * wv.y + ft.z * wv.z + ft.w * wv.w;
        }
    }
    __syncthreads();

    // ---- epilogue: transpose through LDS, coalesced store ----
#pragma unroll
    for (int j = 0; j < 8; ++j)
        smem[(vbase + j) * 65 + o] = acc[j];               // conflict-free
    __syncthreads();
    int vp = threadIdx.x & 31;
    int ob = threadIdx.x >> 5;                             // 0..7
    if (vb + vp < NV) {
#pragma unroll
        for (int r = 0; r < 8; ++r) {
            int o2 = ob + r * 8;
            out[(size_t)o2 * NV + vb + vp] = smem[vp * 65 + o2];
        }
    }
}

// ---------------------------------------------------------------------------
extern "C" void kernel_launch(void* const* d_in, const int* in_sizes, int n_in,
                              void* d_out, int out_size, void* d_ws, size_t ws_size,
                              hipStream_t stream) {
    const float* x        = (const float*)d_in[0];
    const int*   G_cols   = (const int*)  d_in[2];
    const float* G_vals   = (const float*)d_in[3];
    const int*   L_cols   = (const int*)  d_in[5];
    const float* L_vals   = (const float*)d_in[6];
    const int*   F2V_cols = (const int*)  d_in[8];
    const float* F2V_vals = (const float*)d_in[9];
    const float* EW       = (const float*)d_in[10];
    const float* NS       = (const float*)d_in[11];
    const float* coeffs   = (const float*)d_in[12];
    const float* bias     = (const float*)d_in[13];
    float* out = (float*)d_out;
    float* ws  = (float*)d_ws;

    float* coeffsT2 = ws;                                  // 16,384 floats
    float* xin_t    = ws + 16384;                          // NV*64
    float* gf_ew    = xin_t + (size_t)NV * 64;             // NF*64
    float* gf_ns    = gf_ew + (size_t)NF * 64;             // NF*64
    // total ws use: ~50.1 MiB

    k_coeffsT<<<16, 256, 0, stream>>>(coeffs, coeffsT2);
    for (int b = 0; b < 8; ++b) {
        k_transpose<<<641, 256, 0, stream>>>(x + (size_t)b * 64 * NVP, xin_t);
        k_facegrad<<<NF / 4, 256, 0, stream>>>(xin_t, G_cols, G_vals, EW, NS,
                                               gf_ew, gf_ns);
        k_vertex<<<(NV + 31) / 32, 256, 0, stream>>>(
            xin_t, L_cols, L_vals, F2V_cols, F2V_vals, gf_ew, gf_ns,
            coeffsT2, bias, out + (size_t)b * 64 * NV);
    }
}

// Round 2
// 910.232 us; speedup vs baseline: 1.0415x; 1.0415x over previous
//
#include <hip/hip_runtime.h>

#define NVP 10242
#define NV  40962
#define NF  81920
#define CH  64      // CIN = COUT = 64

// ---------------------------------------------------------------------------
// K0: relayout coeffs [o][c][k] -> coeffsT2 [(c*64+o)*4 + k]  (float4 per (c,o))
// ---------------------------------------------------------------------------
__global__ void k_coeffsT(const float* __restrict__ coeffs,
                          float* __restrict__ coeffsT2) {
    int t = blockIdx.x * 256 + threadIdx.x;   // 0..4095  (c*64+o)
    int c = t >> 6, o = t & 63;
    float4 v = *(const float4*)(coeffs + o * 256 + c * 4);
    *(float4*)(coeffsT2 + (size_t)t * 4) = v;
}

// ---------------------------------------------------------------------------
// K1: per-b transpose + pad:  x[c][v] (v<NVP) -> xin_t[v][c], ones for v>=NVP
// ---------------------------------------------------------------------------
__global__ void k_transpose(const float* __restrict__ x,
                            float* __restrict__ xin_t) {
    __shared__ float tile[64][65];           // +1 pad: conflict-free both ways
    int v0 = blockIdx.x * 64;
    int tx = threadIdx.x & 63;
    int ty = threadIdx.x >> 6;               // 0..3
    int v  = v0 + tx;
#pragma unroll
    for (int r = 0; r < 16; ++r) {
        int c = ty + r * 4;
        tile[tx][c] = (v < NVP) ? x[c * NVP + v] : 1.0f;   // coalesced over tx
    }
    __syncthreads();
#pragma unroll
    for (int r = 0; r < 16; ++r) {
        int vl = ty + r * 4;
        int vv = v0 + vl;
        if (vv < NV) xin_t[vv * 64 + tx] = tile[vl][tx];   // coalesced over tx
    }
}

// ---------------------------------------------------------------------------
// K2: per-b face gradients. One wave per face, lane = channel.
// ---------------------------------------------------------------------------
__global__ void __launch_bounds__(256) k_facegrad(
    const float* __restrict__ xin_t,
    const int*   __restrict__ G_cols, const float* __restrict__ G_vals,
    const float* __restrict__ EW,     const float* __restrict__ NS,
    float* __restrict__ gf_ew, float* __restrict__ gf_ns) {
    int f = (blockIdx.x * 256 + threadIdx.x) >> 6;   // global wave id = face
    int c = threadIdx.x & 63;
    float g[3];
#pragma unroll
    for (int d = 0; d < 3; ++d) {
        int base = (d * NF + f) * 3;
        float acc = 0.f;
#pragma unroll
        for (int j = 0; j < 3; ++j) {
            int   col = G_cols[base + j];     // wave-uniform -> broadcast
            float val = G_vals[base + j];
            acc += val * xin_t[col * 64 + c]; // coalesced 256B gather
        }
        g[d] = acc;
    }
    float ew = g[0] * EW[f * 3 + 0] + g[1] * EW[f * 3 + 1] + g[2] * EW[f * 3 + 2];
    float ns = g[0] * NS[f * 3 + 0] + g[1] * NS[f * 3 + 1] + g[2] * NS[f * 3 + 2];
    gf_ew[f * 64 + c] = ew;
    gf_ns[f * 64 + c] = ns;
}

// ---------------------------------------------------------------------------
// K3: per-b vertex kernel. Block = 256 thr (4 waves), tile = 16 vertices.
// Grid 2561/launch (R1 was 1281 @32v -> 24% occupancy, latency-bound).
// LDS 17.4 KB -> 8 blocks/CU (thread-limited) -> 100% occupancy ceiling.
// Phase 1 (lane = c): build feat (xin, lap, gv_ew, gv_ns) -> LDS.
//   smem[c*68 + vloc*4 + k]  (68 = 64+4: 16B-aligned rows, writes <=8-way
//   conflict on 4 instrs total - negligible vs 56 global gathers/lane)
// Phase 2 (lane = o): 4 vertices per wave, feat read as uniform-broadcast b128.
// Epilogue: LDS transpose -> coalesced store to out[o][v].
// ---------------------------------------------------------------------------
#define VPB  16
#define ROWS 68
__global__ void __launch_bounds__(256) k_vertex(
    const float* __restrict__ xin_t,
    const int*   __restrict__ L_cols,   const float* __restrict__ L_vals,
    const int*   __restrict__ F2V_cols, const float* __restrict__ F2V_vals,
    const float* __restrict__ gf_ew,    const float* __restrict__ gf_ns,
    const float* __restrict__ coeffsT2, const float* __restrict__ bias,
    float* __restrict__ out) {
    __shared__ float smem[64 * ROWS];          // 17,408 B; reused for outT
    int w    = threadIdx.x >> 6;               // wave 0..3
    int lane = threadIdx.x & 63;
    int vb   = blockIdx.x * VPB;

    // ---- phase 1: feat build (lane = channel c), 4 vertices per wave ----
    int c = lane;
#pragma unroll
    for (int i = 0; i < 4; ++i) {
        int vloc = w * 4 + i;
        int v    = vb + vloc;
        int vc   = (v < NV) ? v : (NV - 1);
        float f0 = xin_t[vc * 64 + c];
        float lap = 0.f;
        int lb = vc * 7;
#pragma unroll
        for (int j = 0; j < 7; ++j) {
            int   col = L_cols[lb + j];
            float val = L_vals[lb + j];
            lap += val * xin_t[col * 64 + c];
        }
        float ew = 0.f, ns = 0.f;
        int fb = vc * 6;
#pragma unroll
        for (int j = 0; j < 6; ++j) {
            int   col = F2V_cols[fb + j];
            float val = F2V_vals[fb + j];
            ew += val * gf_ew[col * 64 + c];
            ns += val * gf_ns[col * 64 + c];
        }
        *(float4*)&smem[c * ROWS + vloc * 4] = make_float4(f0, lap, ew, ns);
    }
    __syncthreads();

    // ---- phase 2: channel-mix GEMM (lane = o), 4 vertices per wave ----
    int o = lane;
    float acc[4];
    float bo = bias[o];
#pragma unroll
    for (int j = 0; j < 4; ++j) acc[j] = bo;
    int vbase = w * 4;
#pragma unroll 4
    for (int cc = 0; cc < 64; ++cc) {
        float4 wv = *(const float4*)(coeffsT2 + (size_t)(cc * 64 + o) * 4);
        const float* basep = &smem[cc * ROWS + vbase * 4];
#pragma unroll
        for (int j = 0; j < 4; ++j) {
            float4 ft = *(const float4*)(basep + j * 4);   // uniform broadcast
            acc[j] += ft.x * wv.x + ft.y * wv.y + ft.z * wv.z + ft.w * wv.w;
        }
    }
    __syncthreads();

    // ---- epilogue: transpose through LDS, coalesced store ----
#pragma unroll
    for (int j = 0; j < 4; ++j)
        smem[(vbase + j) * 65 + o] = acc[j];               // conflict-free
    __syncthreads();
    int vp = threadIdx.x & 15;                             // 0..15
    int og = threadIdx.x >> 4;                             // 0..15
    if (vb + vp < NV) {
#pragma unroll
        for (int r = 0; r < 4; ++r) {
            int o2 = og + r * 16;
            out[(size_t)o2 * NV + vb + vp] = smem[vp * 65 + o2];
        }
    }
}

// ---------------------------------------------------------------------------
extern "C" void kernel_launch(void* const* d_in, const int* in_sizes, int n_in,
                              void* d_out, int out_size, void* d_ws, size_t ws_size,
                              hipStream_t stream) {
    const float* x        = (const float*)d_in[0];
    const int*   G_cols   = (const int*)  d_in[2];
    const float* G_vals   = (const float*)d_in[3];
    const int*   L_cols   = (const int*)  d_in[5];
    const float* L_vals   = (const float*)d_in[6];
    const int*   F2V_cols = (const int*)  d_in[8];
    const float* F2V_vals = (const float*)d_in[9];
    const float* EW       = (const float*)d_in[10];
    const float* NS       = (const float*)d_in[11];
    const float* coeffs   = (const float*)d_in[12];
    const float* bias     = (const float*)d_in[13];
    float* out = (float*)d_out;
    float* ws  = (float*)d_ws;

    float* coeffsT2 = ws;                                  // 16,384 floats
    float* xin_t    = ws + 16384;                          // NV*64
    float* gf_ew    = xin_t + (size_t)NV * 64;             // NF*64
    float* gf_ns    = gf_ew + (size_t)NF * 64;             // NF*64
    // total ws use: ~50.1 MiB

    k_coeffsT<<<16, 256, 0, stream>>>(coeffs, coeffsT2);
    for (int b = 0; b < 8; ++b) {
        k_transpose<<<641, 256, 0, stream>>>(x + (size_t)b * 64 * NVP, xin_t);
        k_facegrad<<<NF / 4, 256, 0, stream>>>(xin_t, G_cols, G_vals, EW, NS,
                                               gf_ew, gf_ns);
        k_vertex<<<(NV + VPB - 1) / VPB, 256, 0, stream>>>(
            xin_t, L_cols, L_vals, F2V_cols, F2V_vals, gf_ew, gf_ns,
            coeffsT2, bias, out + (size_t)b * 64 * NV);
    }
}

// Round 3
// 814.847 us; speedup vs baseline: 1.1635x; 1.1171x over previous
//
#include <hip/hip_runtime.h>
#include <hip/hip_bf16.h>

typedef __hip_bfloat16 bf16;

#define NVP 10242
#define NV  40962
#define NF  81920

// ---------------------------------------------------------------------------
// K0: relayout coeffs [o][c][k] -> coeffsT2 [(c*64+o)*4 + k]  (float4 per (c,o))
// ---------------------------------------------------------------------------
__global__ void k_coeffsT(const float* __restrict__ coeffs,
                          float* __restrict__ coeffsT2) {
    int t = blockIdx.x * 256 + threadIdx.x;   // 0..4095  (c*64+o)
    int c = t >> 6, o = t & 63;
    float4 v = *(const float4*)(coeffs + o * 256 + c * 4);
    *(float4*)(coeffsT2 + (size_t)t * 4) = v;
}

// ---------------------------------------------------------------------------
// K1: per-b transpose + pad:  x[c][v] fp32 -> xin_t[v][c] bf16, ones for pad
// ---------------------------------------------------------------------------
__global__ void k_transpose(const float* __restrict__ x,
                            bf16* __restrict__ xin_t) {
    __shared__ float tile[64][65];           // +1 pad: conflict-free both ways
    int v0 = blockIdx.x * 64;
    int tx = threadIdx.x & 63;
    int ty = threadIdx.x >> 6;               // 0..3
    int v  = v0 + tx;
#pragma unroll
    for (int r = 0; r < 16; ++r) {
        int c = ty + r * 4;
        tile[tx][c] = (v < NVP) ? x[c * NVP + v] : 1.0f;   // coalesced over tx
    }
    __syncthreads();
#pragma unroll
    for (int r = 0; r < 16; ++r) {
        int vl = ty + r * 4;
        int vv = v0 + vl;
        if (vv < NV) xin_t[vv * 64 + tx] = __float2bfloat16(tile[vl][tx]);
    }
}

// ---------------------------------------------------------------------------
// K2: per-b face gradients. One wave per face, lane = channel. bf16 in/out,
// fp32 accumulate. Each gather = one 128B line (xin_t row).
// ---------------------------------------------------------------------------
__global__ void __launch_bounds__(256) k_facegrad(
    const bf16* __restrict__ xin_t,
    const int*  __restrict__ G_cols, const float* __restrict__ G_vals,
    const float* __restrict__ EW,    const float* __restrict__ NS,
    bf16* __restrict__ gf_ew, bf16* __restrict__ gf_ns) {
    int f = (blockIdx.x * 256 + threadIdx.x) >> 6;   // global wave id = face
    int c = threadIdx.x & 63;
    float g[3];
#pragma unroll
    for (int d = 0; d < 3; ++d) {
        int base = (d * NF + f) * 3;
        float acc = 0.f;
#pragma unroll
        for (int j = 0; j < 3; ++j) {
            int   col = G_cols[base + j];     // wave-uniform -> s_load
            float val = G_vals[base + j];
            acc += val * __bfloat162float(xin_t[col * 64 + c]);
        }
        g[d] = acc;
    }
    float ew = g[0] * EW[f * 3 + 0] + g[1] * EW[f * 3 + 1] + g[2] * EW[f * 3 + 2];
    float ns = g[0] * NS[f * 3 + 0] + g[1] * NS[f * 3 + 1] + g[2] * NS[f * 3 + 2];
    gf_ew[f * 64 + c] = __float2bfloat16(ew);
    gf_ns[f * 64 + c] = __float2bfloat16(ns);
}

// ---------------------------------------------------------------------------
// K3: per-b vertex kernel. Block = 256 thr (4 waves), tile = 16 vertices.
// Phase 1 (lane = c): bf16 gathers (1 line each), fp32 feat -> LDS.
//   smem[c*68 + vloc*4 + k]
// Phase 2 (lane = o): fp32 GEMM, 4 vertices per wave, b128 uniform broadcast.
// Epilogue: LDS transpose -> coalesced store to out[o][v].
// ---------------------------------------------------------------------------
#define VPB  16
#define ROWS 68
__global__ void __launch_bounds__(256) k_vertex(
    const bf16* __restrict__ xin_t,
    const int*  __restrict__ L_cols,   const float* __restrict__ L_vals,
    const int*  __restrict__ F2V_cols, const float* __restrict__ F2V_vals,
    const bf16* __restrict__ gf_ew,    const bf16* __restrict__ gf_ns,
    const float* __restrict__ coeffsT2, const float* __restrict__ bias,
    float* __restrict__ out) {
    __shared__ float smem[64 * ROWS];          // 17,408 B; reused for outT
    int w    = threadIdx.x >> 6;               // wave 0..3
    int lane = threadIdx.x & 63;
    int vb   = blockIdx.x * VPB;

    // ---- phase 1: feat build (lane = channel c), 4 vertices per wave ----
    int c = lane;
#pragma unroll
    for (int i = 0; i < 4; ++i) {
        int vloc = w * 4 + i;
        int v    = vb + vloc;
        int vc   = (v < NV) ? v : (NV - 1);
        float f0 = __bfloat162float(xin_t[vc * 64 + c]);
        float lap = 0.f;
        int lb = vc * 7;
#pragma unroll
        for (int j = 0; j < 7; ++j) {
            int   col = L_cols[lb + j];
            float val = L_vals[lb + j];
            lap += val * __bfloat162float(xin_t[col * 64 + c]);
        }
        float ew = 0.f, ns = 0.f;
        int fb = vc * 6;
#pragma unroll
        for (int j = 0; j < 6; ++j) {
            int   col = F2V_cols[fb + j];
            float val = F2V_vals[fb + j];
            ew += val * __bfloat162float(gf_ew[col * 64 + c]);
            ns += val * __bfloat162float(gf_ns[col * 64 + c]);
        }
        *(float4*)&smem[c * ROWS + vloc * 4] = make_float4(f0, lap, ew, ns);
    }
    __syncthreads();

    // ---- phase 2: channel-mix GEMM (lane = o), 4 vertices per wave ----
    int o = lane;
    float acc[4];
    float bo = bias[o];
#pragma unroll
    for (int j = 0; j < 4; ++j) acc[j] = bo;
    int vbase = w * 4;
#pragma unroll 4
    for (int cc = 0; cc < 64; ++cc) {
        float4 wv = *(const float4*)(coeffsT2 + (size_t)(cc * 64 + o) * 4);
        const float* basep = &smem[cc * ROWS + vbase * 4];
#pragma unroll
        for (int j = 0; j < 4; ++j) {
            float4 ft = *(const float4*)(basep + j * 4);   // uniform broadcast
            acc[j] += ft.x * wv.x + ft.y * wv.y + ft.z * wv.z + ft.w * wv.w;
        }
    }
    __syncthreads();

    // ---- epilogue: transpose through LDS, coalesced store ----
#pragma unroll
    for (int j = 0; j < 4; ++j)
        smem[(vbase + j) * 65 + o] = acc[j];               // conflict-free
    __syncthreads();
    int vp = threadIdx.x & 15;                             // 0..15
    int og = threadIdx.x >> 4;                             // 0..15
    if (vb + vp < NV) {
#pragma unroll
        for (int r = 0; r < 4; ++r) {
            int o2 = og + r * 16;
            out[(size_t)o2 * NV + vb + vp] = smem[vp * 65 + o2];
        }
    }
}

// ---------------------------------------------------------------------------
extern "C" void kernel_launch(void* const* d_in, const int* in_sizes, int n_in,
                              void* d_out, int out_size, void* d_ws, size_t ws_size,
                              hipStream_t stream) {
    const float* x        = (const float*)d_in[0];
    const int*   G_cols   = (const int*)  d_in[2];
    const float* G_vals   = (const float*)d_in[3];
    const int*   L_cols   = (const int*)  d_in[5];
    const float* L_vals   = (const float*)d_in[6];
    const int*   F2V_cols = (const int*)  d_in[8];
    const float* F2V_vals = (const float*)d_in[9];
    const float* EW       = (const float*)d_in[10];
    const float* NS       = (const float*)d_in[11];
    const float* coeffs   = (const float*)d_in[12];
    const float* bias     = (const float*)d_in[13];
    float* out = (float*)d_out;

    char* ws = (char*)d_ws;
    float* coeffsT2 = (float*)ws;                          // 64 KiB
    bf16*  xin_t    = (bf16*)(ws + 65536);                 // NV*64*2  = 5.25 MB
    bf16*  gf_ew    = xin_t + (size_t)NV * 64;             // NF*64*2  = 10.5 MB
    bf16*  gf_ns    = gf_ew + (size_t)NF * 64;             // NF*64*2  = 10.5 MB
    // total ws use: ~26.3 MiB

    k_coeffsT<<<16, 256, 0, stream>>>(coeffs, coeffsT2);
    for (int b = 0; b < 8; ++b) {
        k_transpose<<<641, 256, 0, stream>>>(x + (size_t)b * 64 * NVP, xin_t);
        k_facegrad<<<NF / 4, 256, 0, stream>>>(xin_t, G_cols, G_vals, EW, NS,
                                               gf_ew, gf_ns);
        k_vertex<<<(NV + VPB - 1) / VPB, 256, 0, stream>>>(
            xin_t, L_cols, L_vals, F2V_cols, F2V_vals, gf_ew, gf_ns,
            coeffsT2, bias, out + (size_t)b * 64 * NV);
    }
}

// Round 4
// 469.578 us; speedup vs baseline: 2.0189x; 1.7353x over previous
//
#include <hip/hip_runtime.h>
#include <hip/hip_bf16.h>

typedef __hip_bfloat16 bf16;
typedef __attribute__((ext_vector_type(8))) short short8;
typedef __attribute__((ext_vector_type(4))) float floatx4;

#define NVP 10242
#define NV  40962
#define NF  81920
#define VPB 16

__device__ __forceinline__ float bfbits2f(unsigned short u) {
    union { unsigned int i; float f; } cv; cv.i = ((unsigned int)u) << 16;
    return cv.f;
}
__device__ __forceinline__ unsigned short f2bfbits(float f) {
    bf16 h = __float2bfloat16(f);
    return __builtin_bit_cast(unsigned short, h);
}

// ---------------------------------------------------------------------------
// K0: coeffs [o][c][k] -> coeffsB bf16 in MFMA 16x16x32 B-fragment layout:
//   coeffsB[((ot*8+kk)*64 + lane)*8 + j] = coeffs[o=ot*16+(lane&15)]
//                                                 [kg = kk*32+(lane>>4)*8+j]
//   (kg = c*4 + kidx, i.e. feat k-index is c-major with 4 taps per channel)
// ---------------------------------------------------------------------------
__global__ void k_coeffsB(const float* __restrict__ coeffs,
                          unsigned short* __restrict__ coeffsB) {
    int t = blockIdx.x * 256 + threadIdx.x;       // 0..16383
    int j = t & 7, lane = (t >> 3) & 63, s = t >> 9;   // s = ot*8+kk
    int ot = s >> 3, kk = s & 7;
    int o  = ot * 16 + (lane & 15);
    int kg = kk * 32 + (lane >> 4) * 8 + j;
    coeffsB[t] = f2bfbits(coeffs[o * 256 + kg]);
}

// ---------------------------------------------------------------------------
// K1: per-b transpose + pad: x[c][v] fp32 -> xin[v][c] bf16 bits
// ---------------------------------------------------------------------------
__global__ void k_transpose(const float* __restrict__ x,
                            unsigned short* __restrict__ xin) {
    x   += (size_t)blockIdx.y * 64 * NVP;
    xin += (size_t)blockIdx.y * 64 * NV;
    __shared__ float tile[64][65];
    int v0 = blockIdx.x * 64;
    int tx = threadIdx.x & 63;
    int ty = threadIdx.x >> 6;
    int v  = v0 + tx;
#pragma unroll
    for (int r = 0; r < 16; ++r) {
        int c = ty + r * 4;
        tile[tx][c] = (v < NVP) ? x[c * NVP + v] : 1.0f;
    }
    __syncthreads();
#pragma unroll
    for (int r = 0; r < 16; ++r) {
        int vl = ty + r * 4;
        int vv = v0 + vl;
        if (vv < NV) xin[vv * 64 + tx] = f2bfbits(tile[vl][tx]);
    }
}

// ---------------------------------------------------------------------------
// K2: face gradients. One wave per face, lane = channel.
// fs scalarized via readfirstlane -> G_cols/G_vals/EW/NS become s_loads;
// gather addressing = s_lshl + 1 v_add.
// ---------------------------------------------------------------------------
__global__ void __launch_bounds__(256) k_facegrad(
    const unsigned short* __restrict__ xin,
    const int*   __restrict__ G_cols, const float* __restrict__ G_vals,
    const float* __restrict__ EW,     const float* __restrict__ NS,
    unsigned short* __restrict__ gf_ew, unsigned short* __restrict__ gf_ns) {
    xin   += (size_t)blockIdx.y * 64 * NV;
    gf_ew += (size_t)blockIdx.y * 64 * NF;
    gf_ns += (size_t)blockIdx.y * 64 * NF;
    int f  = (blockIdx.x * 256 + threadIdx.x) >> 6;
    int fs = __builtin_amdgcn_readfirstlane(f);
    int c  = threadIdx.x & 63;
    float g[3];
#pragma unroll
    for (int d = 0; d < 3; ++d) {
        int base = (d * NF + fs) * 3;
        float acc = 0.f;
#pragma unroll
        for (int j = 0; j < 3; ++j) {
            int   col = G_cols[base + j];                // s_load (uniform)
            float val = G_vals[base + j];                // s_load
            acc += val * bfbits2f(xin[col * 64 + c]);
        }
        g[d] = acc;
    }
    float ew = g[0]*EW[fs*3+0] + g[1]*EW[fs*3+1] + g[2]*EW[fs*3+2];
    float ns = g[0]*NS[fs*3+0] + g[1]*NS[fs*3+1] + g[2]*NS[fs*3+2];
    gf_ew[fs * 64 + c] = f2bfbits(ew);
    gf_ns[fs * 64 + c] = f2bfbits(ns);
}

// ---------------------------------------------------------------------------
// K3: vertex kernel. Block 256 (4 waves), 16 vertices.
// Phase 1 (lane=c): scalarized gathers -> feat bf16 in LDS [v][k=256],
//   row stride 264 bf16 (132 dwords == 4 mod 32 -> even bank spread).
// Phase 2: wave w computes o-tile w with 8x mfma_f32_16x16x32_bf16.
// Epilogue: f32 transpose LDS -> coalesced out[o][v] store.
// ---------------------------------------------------------------------------
__global__ void __launch_bounds__(256) k_vertex(
    const unsigned short* __restrict__ xin,
    const int*  __restrict__ L_cols,   const float* __restrict__ L_vals,
    const int*  __restrict__ F2V_cols, const float* __restrict__ F2V_vals,
    const unsigned short* __restrict__ gf_ew,
    const unsigned short* __restrict__ gf_ns,
    const unsigned short* __restrict__ coeffsB,
    const float* __restrict__ bias,
    float* __restrict__ out) {
    xin   += (size_t)blockIdx.y * 64 * NV;
    gf_ew += (size_t)blockIdx.y * 64 * NF;
    gf_ns += (size_t)blockIdx.y * 64 * NF;
    out   += (size_t)blockIdx.y * 64 * NV;

    __shared__ unsigned short feat[VPB * 264];   // 8448 B
    __shared__ float outs[VPB * 65];             // 4160 B
    int w    = threadIdx.x >> 6;
    int lane = threadIdx.x & 63;
    int vb   = blockIdx.x * VPB;
    int c    = lane;

    // ---- phase 1: feat build, 4 vertices per wave, scalarized indices ----
#pragma unroll
    for (int i = 0; i < 4; ++i) {
        int vloc = w * 4 + i;
        int v    = vb + vloc;
        int vcs  = __builtin_amdgcn_readfirstlane(v < NV ? v : NV - 1);
        float f0 = bfbits2f(xin[vcs * 64 + c]);
        float lap = 0.f;
        int lb = vcs * 7;
#pragma unroll
        for (int j = 0; j < 7; ++j) {
            int   col = L_cols[lb + j];                  // s_load
            float val = L_vals[lb + j];                  // s_load
            lap += val * bfbits2f(xin[col * 64 + c]);
        }
        float ew = 0.f, ns = 0.f;
        int fb = vcs * 6;
#pragma unroll
        for (int j = 0; j < 6; ++j) {
            int   col = F2V_cols[fb + j];                // s_load
            float val = F2V_vals[fb + j];                // s_load
            ew += val * bfbits2f(gf_ew[col * 64 + c]);
            ns += val * bfbits2f(gf_ns[col * 64 + c]);
        }
        ushort4 p = make_ushort4(f2bfbits(f0), f2bfbits(lap),
                                 f2bfbits(ew), f2bfbits(ns));
        *(ushort4*)&feat[vloc * 264 + c * 4] = p;        // 8B, 2-way (free)
    }
    __syncthreads();

    // ---- phase 2: MFMA, wave w -> o-tile w (o = w*16 .. w*16+15) ----
    int m = lane & 15, quad = lane >> 4;
    float bo = bias[w * 16 + m];
    floatx4 acc = {bo, bo, bo, bo};
#pragma unroll
    for (int kk = 0; kk < 8; ++kk) {
        short8 a = *(const short8*)&feat[m * 264 + kk * 32 + quad * 8];
        short8 b = *(const short8*)&coeffsB[((w * 8 + kk) * 64 + lane) * 8];
        acc = __builtin_amdgcn_mfma_f32_16x16x32_bf16(a, b, acc, 0, 0, 0);
    }

    // ---- epilogue: C layout col=lane&15 (o), row=quad*4+reg (v) ----
#pragma unroll
    for (int r = 0; r < 4; ++r)
        outs[(quad * 4 + r) * 65 + w * 16 + m] = acc[r];
    __syncthreads();
    int vp = threadIdx.x & 15;
    int og = threadIdx.x >> 4;
    if (vb + vp < NV) {
#pragma unroll
        for (int r = 0; r < 4; ++r) {
            int o2 = og + r * 16;
            out[(size_t)o2 * NV + vb + vp] = outs[vp * 65 + o2];
        }
    }
}

// ---------------------------------------------------------------------------
extern "C" void kernel_launch(void* const* d_in, const int* in_sizes, int n_in,
                              void* d_out, int out_size, void* d_ws, size_t ws_size,
                              hipStream_t stream) {
    const float* x        = (const float*)d_in[0];
    const int*   G_cols   = (const int*)  d_in[2];
    const float* G_vals   = (const float*)d_in[3];
    const int*   L_cols   = (const int*)  d_in[5];
    const float* L_vals   = (const float*)d_in[6];
    const int*   F2V_cols = (const int*)  d_in[8];
    const float* F2V_vals = (const float*)d_in[9];
    const float* EW       = (const float*)d_in[10];
    const float* NS       = (const float*)d_in[11];
    const float* coeffs   = (const float*)d_in[12];
    const float* bias     = (const float*)d_in[13];
    float* out = (float*)d_out;

    char* ws = (char*)d_ws;
    const size_t xin_b = (size_t)NV * 64;   // elements per batch
    const size_t gf_b  = (size_t)NF * 64;
    // ws-size-adaptive batching (path fixed for a given ws_size -> graph-safe)
    size_t need8 = 65536 + (8 * xin_b + 16 * gf_b) * 2;   // ~210 MB
    size_t need2 = 65536 + (2 * xin_b + 4 * gf_b) * 2;    // ~52.6 MB
    int nb = (ws_size >= need8) ? 8 : (ws_size >= need2) ? 2 : 1;

    unsigned short* coeffsB = (unsigned short*)ws;          // 32 KB
    unsigned short* xin = (unsigned short*)(ws + 65536);    // nb * 5.25 MB
    unsigned short* gfe = xin + (size_t)nb * xin_b;         // nb * 10.5 MB
    unsigned short* gfn = gfe + (size_t)nb * gf_b;          // nb * 10.5 MB

    k_coeffsB<<<64, 256, 0, stream>>>(coeffs, coeffsB);
    for (int b0 = 0; b0 < 8; b0 += nb) {
        dim3 gt(641, nb), gg(NF / 4, nb), gv((NV + VPB - 1) / VPB, nb);
        k_transpose<<<gt, 256, 0, stream>>>(x + (size_t)b0 * 64 * NVP, xin);
        k_facegrad<<<gg, 256, 0, stream>>>(xin, G_cols, G_vals, EW, NS, gfe, gfn);
        k_vertex<<<gv, 256, 0, stream>>>(xin, L_cols, L_vals, F2V_cols, F2V_vals,
                                         gfe, gfn, coeffsB, bias,
                                         out + (size_t)b0 * 64 * NV);
    }
}